// Round 18
// baseline (175.056 us; speedup 1.0000x reference)
//
#include <hip/hip_runtime.h>
#include <cstdint>

#define NP   4096      // patches
#define DD   768       // embed dim
#define HD   64
#define WD   64
#define KTOP 100

typedef short bf16x8 __attribute__((ext_vector_type(8)));
typedef float f32x4  __attribute__((ext_vector_type(4)));

__device__ __forceinline__ void gload_lds16(const void* g, void* l) {
    __builtin_amdgcn_global_load_lds(
        (const __attribute__((address_space(1))) unsigned int*)(uintptr_t)g,
        (__attribute__((address_space(3))) unsigned int*)(unsigned int)(uintptr_t)l,
        16, 0, 0);
}

__device__ __forceinline__ unsigned short f2bf_rne(float x) {
    unsigned b = __float_as_uint(x);
    unsigned r = b + 0x7FFFu + ((b >> 16) & 1u);
    return (unsigned short)(r >> 16);
}
__device__ __forceinline__ float bf2f(unsigned short h) {
    return __uint_as_float(((unsigned)h) << 16);
}

// ---------------- kernel 1: split A into bf16 hi+lo; zero counts ----------------
__global__ __launch_bounds__(256) void k_split(const float* __restrict__ A,
                                               unsigned short* __restrict__ hi,
                                               unsigned short* __restrict__ lo,
                                               int* __restrict__ counts) {
    if (blockIdx.x < 16) counts[blockIdx.x * 256 + threadIdx.x] = 0;
    int idx = blockIdx.x * 256 + threadIdx.x;       // float4 index
    float4 v = ((const float4*)A)[idx];
    unsigned short h0 = f2bf_rne(v.x), h1 = f2bf_rne(v.y),
                   h2 = f2bf_rne(v.z), h3 = f2bf_rne(v.w);
    unsigned short l0 = f2bf_rne(v.x - bf2f(h0)), l1 = f2bf_rne(v.y - bf2f(h1)),
                   l2 = f2bf_rne(v.z - bf2f(h2)), l3 = f2bf_rne(v.w - bf2f(h3));
    ((ushort4*)hi)[idx] = make_ushort4(h0, h1, h2, h3);
    ((ushort4*)lo)[idx] = make_ushort4(l0, l1, l2, l3);
}

// ---------------- kernel 2: split-bf16 MFMA GEMM, mixed-granularity, BK=64 ----------
// R18: BK=64 on the FULL path too (12 iterations instead of 24). The calibrated
// cost model (fixed ~5us @24 barrier-iters + 14us staging; eighth tiles at 12
// iters confirmed the fixed term halves) predicts full-tile 19.1 -> ~16.5us.
// Buffer packs two 32-K windows [win0: A1024|B1024][win1: ...] = 64 KB; dbuf =
// 128 KB (already 1 block/CU, so no occupancy loss). colc/rowc reuse G after
// the loop (R3-proven) -> LDS exactly 131072 (R10 compiled this size).
// Per iter the two windows run sequentially with the identical per-window
// hihi->lohi->hilo chain -> global K-order and per-element accumulation
// UNCHANGED -> bit-identical (same argument as the eighth path, absmax 0).
// Tail = 124 eighth tiles (64x32, BK=64) verbatim from R16/R17.
__device__ __forceinline__ void stage_full64(const unsigned short* __restrict__ hi,
                                             const unsigned short* __restrict__ lo,
                                             int i0, int j0, int kbase, int tid,
                                             unsigned short* G) {
#pragma unroll
    for (int q = 0; q < 8; ++q) {
        int pp = q * 512 + tid;                  // 0..4095
        int ww = (pp >= 2048) ? 1 : 0;           // 32-K window
        int ppt = pp & 2047;                     // within window
        int isB = ppt >= 1024;
        int row = (ppt & 1023) >> 3;             // 0..127
        int kcl = (ppt & 7) ^ (row & 7);         // logical chunk (inverse of swizzle)
        int rbase = isB ? j0 : i0;
        const unsigned short* src =
            ((kcl < 4) ? hi : lo) + (size_t)(rbase + row) * DD
            + kbase + ww * 32 + (kcl & 3) * 8;
        gload_lds16(src, G + pp * 8);
    }
}

// eighth tile (64 A-rows, 32 B-rows), BK=64: 1536 chunks/buffer, 3 per thread
__device__ __forceinline__ void stage_eighth(const unsigned short* __restrict__ hi,
                                             const unsigned short* __restrict__ lo,
                                             int i0, int j0, int kbase, int tid,
                                             unsigned short* G) {
#pragma unroll
    for (int q = 0; q < 3; ++q) {
        int pp = q * 512 + tid;                  // 0..1535
        int ww = (pp >= 768) ? 1 : 0;            // 32-K window
        int ppt = pp - ww * 768;                 // 0..767 within window
        int isB = ppt >= 512;
        int rowp = (isB ? (ppt - 512) : ppt) >> 3;   // A:0..63  B:0..31
        int kcl = (ppt & 7) ^ (rowp & 7);
        int rbase = isB ? j0 : i0;
        const unsigned short* src =
            ((kcl < 4) ? hi : lo) + (size_t)(rbase + rowp) * DD
            + kbase + ww * 32 + (kcl & 3) * 8;
        gload_lds16(src, G + pp * 8);
    }
}

__global__ __launch_bounds__(512, 4) void k_gemm(const unsigned short* __restrict__ hi,
                                                 const unsigned short* __restrict__ lo,
                                                 int* __restrict__ counts) {
    __shared__ __align__(16) unsigned short G[2][4096 * 8];   // 2 x 64 KB

    int job = blockIdx.x;
    int p, er = 0, ec = 0, offd_tail = 1;
    if (job < 512) {
        p = job;
    } else {
        int r = job - 512;                       // 0..123
        p = 512;
        for (;;) {
            int nj = (p == 523 || p == 527) ? 6 : 8;
            if (r < nj) break;
            r -= nj; ++p;
        }
        if (p == 523 || p == 527) {
            // 0:(0,0)D 1:(0,1)D 2:(1,2)D 3:(1,3)D 4:(0,2)O 5:(0,3)O
            if (r < 4) { er = r >> 1; ec = (r >> 1) * 2 + (r & 1); offd_tail = 0; }
            else       { er = 0; ec = r - 2; offd_tail = 1; }
        } else {
            er = r >> 2; ec = r & 3; offd_tail = 1;
        }
    }

    // XCD-locality supertile remap (bijective over 0..527):
    int t = ((p & 7) * 66) + (p >> 3);
    int SI = 0, SJ = 0, rem = t;
    for (;;) {
        int sz = (SI == SJ) ? 36 : 64;
        if (rem < sz) break;
        rem -= sz;
        if (++SJ == 4) { ++SI; SJ = SI; }
    }
    int li, lj;
    if (SI == SJ) {
        int r2 = 0;
        while (rem >= (8 - r2)) { rem -= (8 - r2); ++r2; }
        li = r2; lj = r2 + rem;
    } else { li = rem >> 3; lj = rem & 7; }
    int bi = SI * 8 + li, bj = SJ * 8 + lj;

    int tid = threadIdx.x;
    int lane = tid & 63, w = tid >> 6;   // w 0..7
    int kcf = lane >> 4;                 // 0..3
    int nl = lane & 15;                  // col within 16x16 tile
    int rg = lane >> 4;                  // row group (rows rg*4 + g)

    int* colc = (int*)&G[0][0];          // reused post-loop (R3 pattern)
    int* rowc = ((int*)&G[0][0]) + 128;

    if (job < 512) {
        // ---------------- FULL 128x128 path, BK=64 (12 iterations) ----------------
        int wm = w & 1, wn = w >> 1;
        int i0 = bi * 128, j0 = bj * 128;
        int offd = (bi != bj);
        int paH[4], paL[4], pbH[2], pbL[2];   // window-0 chunk offsets
#pragma unroll
        for (int tt = 0; tt < 4; ++tt) {
            int arow = wm * 64 + tt * 16 + (lane & 15);
            paH[tt] = arow * 8 + (kcf ^ (arow & 7));
            paL[tt] = arow * 8 + ((kcf + 4) ^ (arow & 7));
        }
#pragma unroll
        for (int u = 0; u < 2; ++u) {
            int brow = wn * 32 + u * 16 + (lane & 15);
            pbH[u] = 1024 + brow * 8 + (kcf ^ (brow & 7));
            pbL[u] = 1024 + brow * 8 + ((kcf + 4) ^ (brow & 7));
        }
        f32x4 acc[4][2];
#pragma unroll
        for (int ti = 0; ti < 4; ++ti)
#pragma unroll
            for (int u = 0; u < 2; ++u) { acc[ti][u][0] = 0.f; acc[ti][u][1] = 0.f;
                                          acc[ti][u][2] = 0.f; acc[ti][u][3] = 0.f; }

        stage_full64(hi, lo, i0, j0, 0, tid, G[0]);
        for (int it = 0; it < 12; ++it) {
            int cur = it & 1;
            __syncthreads();   // buf[cur] loads done; prev compute on buf[cur^1] done
            if (it + 1 < 12)
                stage_full64(hi, lo, i0, j0, (it + 1) * 64, tid, G[cur ^ 1]);
#pragma unroll
            for (int ww = 0; ww < 2; ++ww) {   // two 32-K windows, in K order
                const int wo = ww * 2048 * 8;  // short offset of window
                bf16x8 ahi[4], alo[4], bhi[2], blo[2];
#pragma unroll
                for (int tt = 0; tt < 4; ++tt) {
                    ahi[tt] = *(const bf16x8*)&G[cur][wo + paH[tt] * 8];
                    alo[tt] = *(const bf16x8*)&G[cur][wo + paL[tt] * 8];
                }
#pragma unroll
                for (int u = 0; u < 2; ++u) {
                    bhi[u] = *(const bf16x8*)&G[cur][wo + pbH[u] * 8];
                    blo[u] = *(const bf16x8*)&G[cur][wo + pbL[u] * 8];
                }
#pragma unroll
                for (int ti = 0; ti < 4; ++ti)
#pragma unroll
                    for (int u = 0; u < 2; ++u) {
                        acc[ti][u] = __builtin_amdgcn_mfma_f32_16x16x32_bf16(
                            ahi[ti], bhi[u], acc[ti][u], 0, 0, 0);
                        acc[ti][u] = __builtin_amdgcn_mfma_f32_16x16x32_bf16(
                            alo[ti], bhi[u], acc[ti][u], 0, 0, 0);
                        acc[ti][u] = __builtin_amdgcn_mfma_f32_16x16x32_bf16(
                            ahi[ti], blo[u], acc[ti][u], 0, 0, 0);
                    }
            }
        }

        __syncthreads();                       // loop done: reuse G for reductions
        if (tid < 128) { colc[tid] = 0; rowc[tid] = 0; }
        __syncthreads();
        int cc[2] = {0, 0};
#pragma unroll
        for (int ti = 0; ti < 4; ++ti)
#pragma unroll
            for (int u = 0; u < 2; ++u) {
                f32x4 a = acc[ti][u];
                cc[u] += ((a[0] >= 0.f) ? 1 : 0) + ((a[1] >= 0.f) ? 1 : 0) +
                         ((a[2] >= 0.f) ? 1 : 0) + ((a[3] >= 0.f) ? 1 : 0);
            }
#pragma unroll
        for (int u = 0; u < 2; ++u) {
            int v = cc[u];
            v += __shfl_xor(v, 16);
            v += __shfl_xor(v, 32);
            if (rg == 0) atomicAdd(&colc[wn * 32 + u * 16 + nl], v);
        }
        if (offd) {
#pragma unroll
            for (int ti = 0; ti < 4; ++ti)
#pragma unroll
                for (int g = 0; g < 4; ++g) {
                    int rv = ((acc[ti][0][g] >= 0.f) ? 1 : 0) +
                             ((acc[ti][1][g] >= 0.f) ? 1 : 0);
                    rv += __shfl_xor(rv, 1);
                    rv += __shfl_xor(rv, 2);
                    rv += __shfl_xor(rv, 4);
                    rv += __shfl_xor(rv, 8);
                    if (nl == 0) atomicAdd(&rowc[wm * 64 + ti * 16 + rg * 4 + g], rv);
                }
        }
        __syncthreads();
        if (tid < 128) {
            atomicAdd(&counts[j0 + tid], colc[tid]);
            if (offd) atomicAdd(&counts[i0 + tid], rowc[tid]);
        }
    } else {
        // ---------------- EIGHTH 64x32 path, BK=64 (tail round) ----------------
        int wm2 = w >> 1, wn2 = w & 1;           // row group x16 (0..3), col group x16 (0..1)
        int i0 = bi * 128 + er * 64, j0 = bj * 128 + ec * 32;
        int offd = offd_tail;

        int arow = wm2 * 16 + (lane & 15);       // 0..63
        int brow = wn2 * 16 + (lane & 15);       // 0..31
        int paH[2], paL[2], pbH[2], pbL[2];
#pragma unroll
        for (int ww = 0; ww < 2; ++ww) {
            paH[ww] = ww * 768 + arow * 8 + (kcf ^ (arow & 7));
            paL[ww] = ww * 768 + arow * 8 + ((kcf + 4) ^ (arow & 7));
            pbH[ww] = ww * 768 + 512 + brow * 8 + (kcf ^ (brow & 7));
            pbL[ww] = ww * 768 + 512 + brow * 8 + ((kcf + 4) ^ (brow & 7));
        }

        f32x4 acc = {0.f, 0.f, 0.f, 0.f};

        stage_eighth(hi, lo, i0, j0, 0, tid, G[0]);
        for (int it = 0; it < 12; ++it) {
            int cur = it & 1;
            __syncthreads();
            if (it + 1 < 12)
                stage_eighth(hi, lo, i0, j0, (it + 1) * 64, tid, G[cur ^ 1]);
#pragma unroll
            for (int ww = 0; ww < 2; ++ww) {
                bf16x8 ah = *(const bf16x8*)&G[cur][paH[ww] * 8];
                bf16x8 al = *(const bf16x8*)&G[cur][paL[ww] * 8];
                bf16x8 bh = *(const bf16x8*)&G[cur][pbH[ww] * 8];
                bf16x8 bl = *(const bf16x8*)&G[cur][pbL[ww] * 8];
                acc = __builtin_amdgcn_mfma_f32_16x16x32_bf16(ah, bh, acc, 0, 0, 0);
                acc = __builtin_amdgcn_mfma_f32_16x16x32_bf16(al, bh, acc, 0, 0, 0);
                acc = __builtin_amdgcn_mfma_f32_16x16x32_bf16(ah, bl, acc, 0, 0, 0);
            }
        }

        __syncthreads();                   // loop done: reuse G
        int* colq = colc;                  // 32 ints
        int* rowq = colc + 32;             // 64 ints
        if (tid < 96) colc[tid] = 0;
        __syncthreads();
        {
            int v = ((acc[0] >= 0.f) ? 1 : 0) + ((acc[1] >= 0.f) ? 1 : 0) +
                    ((acc[2] >= 0.f) ? 1 : 0) + ((acc[3] >= 0.f) ? 1 : 0);
            v += __shfl_xor(v, 16);
            v += __shfl_xor(v, 32);
            if (rg == 0) atomicAdd(&colq[wn2 * 16 + nl], v);
        }
        if (offd) {
#pragma unroll
            for (int g = 0; g < 4; ++g) {
                int rv = ((acc[g] >= 0.f) ? 1 : 0);
                rv += __shfl_xor(rv, 1);
                rv += __shfl_xor(rv, 2);
                rv += __shfl_xor(rv, 4);
                rv += __shfl_xor(rv, 8);
                if (nl == 0) atomicAdd(&rowq[wm2 * 16 + rg * 4 + g], rv);
            }
        }
        __syncthreads();
        if (tid < 32) atomicAdd(&counts[j0 + tid], colq[tid]);
        if (tid < 64 && offd) atomicAdd(&counts[i0 + tid], rowq[tid]);
    }
}

// ---------------- shared helpers (8-wave, 512 threads) ----------------
__device__ __forceinline__ int block_sum512(int v, int lane, int w, int* wred) {
#pragma unroll
    for (int o = 1; o < 64; o <<= 1) v += __shfl_xor(v, o);
    if (lane == 0) wred[w] = v;
    __syncthreads();
    int tt = 0;
#pragma unroll
    for (int i = 0; i < 8; ++i) tt += wred[i];
    __syncthreads();
    return tt;
}
__device__ __forceinline__ int block_exscan512(int v, int lane, int w, int* wred,
                                               int* total) {
    int inc = v;
#pragma unroll
    for (int o = 1; o < 64; o <<= 1) { int u = __shfl_up(inc, o); if (lane >= o) inc += u; }
    if (lane == 63) wred[w] = inc;
    __syncthreads();
    int wofs = 0, tot = 0;
#pragma unroll
    for (int i = 0; i < 8; ++i) { int x = wred[i]; if (i < w) wofs += x; tot += x; }
    *total = tot;
    __syncthreads();
    return wofs + inc - v;   // exclusive
}

// ---------------- kernel 3: argmin seed (packed-key wave-min) + simrow + zero outp ----
// 512 blocks (8 rows each, 2 rows/wave). Argmin via key=(count<<12|j) min
// (lexicographic: min count then min index -- identical tie-break), ONE barrier.
__global__ __launch_bounds__(256) void k_seedrow(const float* __restrict__ A,
                                                 const int* __restrict__ counts,
                                                 const int* __restrict__ attn_seed,
                                                 float* __restrict__ simrow,
                                                 int* __restrict__ seedp,
                                                 int* __restrict__ outp) {
    __shared__ unsigned redw[4];
    int tid = threadIdx.x, lane = tid & 63, w = tid >> 6;
    int blk = blockIdx.x;

    unsigned bk = 0xFFFFFFFFu;
    for (int j = tid; j < NP; j += 256) {
        unsigned k2 = ((unsigned)counts[j] << 12) | (unsigned)j;   // c<=4096 -> 25 bits
        bk = min(bk, k2);
    }
#pragma unroll
    for (int o = 1; o < 64; o <<= 1) {
        unsigned ok = __shfl_xor(bk, o);
        bk = min(bk, ok);
    }
    if (lane == 0) redw[w] = bk;
    __syncthreads();
    unsigned m0 = min(min(redw[0], redw[1]), min(redw[2], redw[3]));
    int flat = (int)(m0 & 0xFFFu);

    int sr = flat / WD, sc = flat % WD;
    int vr = sr + attn_seed[0];
    int vc = sc + attn_seed[1];
    int rr, rc;
    if ((vr & 1) == 0) rr = vr >> 1;
    else { int m = vr >> 1; rr = (m & 1) ? m + 1 : m; }   // round-half-to-even
    if ((vc & 1) == 0) rc = vc >> 1;
    else { int m = vc >> 1; rc = (m & 1) ? m + 1 : m; }
    int seed = rr * WD + rc;
    if (blk == 0 && tid == 0) seedp[0] = seed;

    float sv[12];
#pragma unroll
    for (int kk = 0; kk < 12; ++kk) sv[kk] = A[(size_t)seed * DD + lane + kk * 64];
    int jbase = blk * 8 + w * 2;
#pragma unroll
    for (int jj = 0; jj < 2; ++jj) {
        int j = jbase + jj;
        float sum = 0.f;
#pragma unroll
        for (int kk = 0; kk < 12; ++kk)
            sum += sv[kk] * A[(size_t)j * DD + lane + kk * 64];
#pragma unroll
        for (int o = 32; o > 0; o >>= 1) sum += __shfl_down(sum, o);
        if (lane == 0) simrow[j] = sum;
    }
    if (blk < 128 && tid < 32) outp[blk * 32 + tid] = 0;
}

// ---------------- kernel 4: fused top-K select + subsim row (128 blocks, 512 thr) ----
// 8 waves: radix on 8 keys/thread; subsim q-loop q+=8 (13 serial iterations).
// Selection invariants unchanged (ascending-j key blocks per tid order).
__global__ __launch_bounds__(512) void k_subsel(const float* __restrict__ A,
                                                const float* __restrict__ simrow,
                                                const int* __restrict__ seedp,
                                                int* __restrict__ act, int* __restrict__ Mp,
                                                float* __restrict__ subsim) {
    __shared__ int wred[8];
    __shared__ unsigned long long rsl[16][8];
    __shared__ int act_s[128];
    __shared__ float av[DD];
    int tid = threadIdx.x, lane = tid & 63, w = tid >> 6;   // w 0..7
    int seed = seedp[0];
    int base = tid * 8;
    unsigned key[8];
#pragma unroll
    for (int n = 0; n < 8; ++n) {
        unsigned b = __float_as_uint(simrow[base + n]);
        key[n] = (b & 0x80000000u) ? ~b : (b | 0x80000000u);   // monotone encode
    }
    unsigned prefix = 0;
    for (int pass = 0; pass < 16; ++pass) {
        int shift = 30 - pass * 2;
        unsigned phi = prefix >> shift;        // low 2 bits zero
        int s0 = 0, s1 = 0, s2 = 0, s3 = 0;
#pragma unroll
        for (int n = 0; n < 8; ++n) {
            unsigned hv = key[n] >> shift;
            s0 += (hv >= phi) ? 1 : 0;
            s1 += (hv >= phi + 1) ? 1 : 0;
            s2 += (hv >= phi + 2) ? 1 : 0;
            s3 += (hv >= phi + 3) ? 1 : 0;
        }
        unsigned long long pk = (unsigned long long)(unsigned)s0 |
                                ((unsigned long long)(unsigned)s1 << 16) |
                                ((unsigned long long)(unsigned)s2 << 32) |
                                ((unsigned long long)(unsigned)s3 << 48);
#pragma unroll
        for (int o = 1; o < 64; o <<= 1) {
            unsigned lo2 = __shfl_xor((unsigned)pk, o);
            unsigned hi2 = __shfl_xor((unsigned)(pk >> 32), o);
            pk += ((unsigned long long)hi2 << 32) | lo2;   // fields<=4096: no carry-out
        }
        if (lane == 0) rsl[pass][w] = pk;
        __syncthreads();
        unsigned long long tot = 0;
#pragma unroll
        for (int i = 0; i < 8; ++i) tot += rsl[pass][i];
        int c1 = (int)((tot >> 16) & 0xFFFF);
        int c2 = (int)((tot >> 32) & 0xFFFF);
        int c3 = (int)((tot >> 48) & 0xFFFF);
        int d = (c3 >= KTOP) ? 3 : (c2 >= KTOP) ? 2 : (c1 >= KTOP) ? 1 : 0;
        prefix |= (unsigned)d << shift;
    }
    unsigned KT = prefix;
    int cgt = 0, ceq = 0;
#pragma unroll
    for (int n = 0; n < 8; ++n) {
        cgt += (key[n] > KT) ? 1 : 0;
        ceq += (key[n] == KT) ? 1 : 0;
    }
    int totgt = block_sum512(cgt, lane, w, wred);
    int slots = KTOP - totgt;
    int dummy;
    int eqrun = block_exscan512(ceq, lane, w, wred, &dummy);
    int flag[8]; int cf = 0;
#pragma unroll
    for (int n = 0; n < 8; ++n) {
        int j = base + n;
        unsigned k = key[n];
        int topk = (k > KT) || (k == KT && eqrun < slots);
        if (k == KT) ++eqrun;
        int f = (topk && (k >= 0x80000000u || j == seed)) ? 1 : 0;
        flag[n] = f; cf += f;
    }
    int M;
    int off = block_exscan512(cf, lane, w, wred, &M);
#pragma unroll
    for (int n = 0; n < 8; ++n)
        if (flag[n]) act_s[off++] = base + n;
    __syncthreads();

    int p = blockIdx.x;
    if (p == 0) {
        if (tid == 0) Mp[0] = M;
        if (tid < M) act[tid] = act_s[tid];
    }
    if (p >= M) return;

    int ip = act_s[p];
    for (int k = tid; k < DD; k += 512) av[k] = A[(size_t)ip * DD + k];
    __syncthreads();
    for (int q = w; q < M; q += 8) {
        int iq = act_s[q];
        float sum = 0.f;
#pragma unroll
        for (int kk = 0; kk < 12; ++kk) {
            int k = lane + kk * 64;
            sum += av[k] * A[(size_t)iq * DD + k];
        }
#pragma unroll
        for (int o = 32; o > 0; o >>= 1) sum += __shfl_down(sum, o);
        if (lane == 0) subsim[p * 128 + q] = sum;
    }
}

// ---------------- kernel 5: expansion scan + CC (1 block) ----------------
__global__ __launch_bounds__(256) void k_fin(const float* __restrict__ subsim,
                                             const int* __restrict__ act,
                                             const int* __restrict__ Mp,
                                             int* __restrict__ outp) {
    __shared__ float ss[128 * 128];   // 64 KB, transposed+rotated
    __shared__ int act_s[128];
    __shared__ int alive[128];
    __shared__ int lab[128];
    __shared__ unsigned char nbr[128][8];
    __shared__ int ncnt[128];
    __shared__ int chg;
    int M = Mp[0];
    int tid = threadIdx.x, lane = tid & 63;

    if (tid < 128) act_s[tid] = (tid < M) ? act[tid] : 0;
    // ssT(q,p) at ss[q*128 + ((p+q)&127)]: conflict-free writes & column reads
    for (int i4 = tid; i4 < M * 32; i4 += 256) {
        int p = i4 >> 5, qb = (i4 & 31) << 2;
        float4 v = ((const float4*)subsim)[i4];
        ss[(qb + 0) * 128 + ((p + qb + 0) & 127)] = v.x;
        ss[(qb + 1) * 128 + ((p + qb + 1) & 127)] = v.y;
        ss[(qb + 2) * 128 + ((p + qb + 2) & 127)] = v.z;
        ss[(qb + 3) * 128 + ((p + qb + 3) & 127)] = v.w;
    }
    __syncthreads();

    // expansion scan with incremental sums
    if (tid < 64) {
        float S_lo = 0.f, S_hi = 0.f;
        for (int q = 0; q < M; ++q) {
            S_lo += ss[q * 128 + ((lane + q) & 127)];
            S_hi += ss[q * 128 + ((lane + 64 + q) & 127)];
        }
        float al = (lane < M) ? 1.f : 0.f;
        float ah = (lane + 64 < M) ? 1.f : 0.f;
        for (int p = 0; p < M; ++p) {
            float Sp = (p < 64) ? __shfl(S_lo, p) : __shfl(S_hi, p - 64);
            if (!(Sp > 0.f)) {   // node p dies: remove its column from all sums
                S_lo -= ss[p * 128 + ((lane + p) & 127)];
                S_hi -= ss[p * 128 + ((lane + 64 + p) & 127)];
                if (lane == p)      al = 0.f;
                if (lane + 64 == p) ah = 0.f;
            }
        }
        alive[lane]      = (lane < M && al != 0.f) ? 1 : 0;
        alive[lane + 64] = (lane + 64 < M && ah != 0.f) ? 1 : 0;
    }
    __syncthreads();

    // CC: neighbor lists + hook/pointer-jump
    if (tid < 128) {
        int a = (tid < M) ? alive[tid] : 0;
        int c = 0;
        if (a) {
            int id = act_s[tid];
            int y = id >> 6, x = id & 63;
            for (int q = 0; q < M; ++q) {
                if (q == tid || !alive[q]) continue;
                int qid = act_s[q];
                int dy = (qid >> 6) - y, dx = (qid & 63) - x;
                if (dy >= -1 && dy <= 1 && dx >= -1 && dx <= 1)
                    nbr[tid][c++] = (unsigned char)q;
            }
        }
        ncnt[tid] = c;
        lab[tid] = a ? tid : 32767;
    }
    __syncthreads();
    while (true) {
        if (tid == 0) chg = 0;
        __syncthreads();
        int local = 0;
        if (tid < M && alive[tid]) {
            int m = lab[tid];
            int nc = ncnt[tid];
            for (int k = 0; k < nc; ++k) { int u = lab[nbr[tid][k]]; if (u < m) m = u; }
            { int u = lab[m]; if (u < m) m = u; }   // jump
            { int u = lab[m]; if (u < m) m = u; }   // jump again
            if (m < lab[tid]) { lab[tid] = m; local = 1; }
        }
        if (local) chg = 1;
        __syncthreads();
        if (chg == 0) break;
        __syncthreads();
    }
    if (tid < M && alive[tid]) outp[act_s[tid]] = act_s[lab[tid]] + 1;
}

extern "C" void kernel_launch(void* const* d_in, const int* in_sizes, int n_in,
                              void* d_out, int out_size, void* d_ws, size_t ws_size,
                              hipStream_t stream) {
    const float* A = (const float*)d_in[0];       // out: (4096, 768) fp32
    const int* attn = (const int*)d_in[1];        // attn_seed: (2,) int32
    int* outp = (int*)d_out;                      // labels: (64,64) int32

    char* ws = (char*)d_ws;
    int*            counts = (int*)(ws);                    // 16 KB
    float*          simrow = (float*)(ws + 16384);          // 16 KB
    int*            act    = (int*)(ws + 32768);            // 512 B
    int*            Mp     = (int*)(ws + 33280);
    int*            seedp  = (int*)(ws + 33284);
    float*          subsim = (float*)(ws + 33792);          // 64 KB
    unsigned short* hi     = (unsigned short*)(ws + 1048576);           // 6.29 MB
    unsigned short* lo     = (unsigned short*)(ws + 1048576 + 6291456); // 6.29 MB

    k_split  <<<3072, 256, 0, stream>>>(A, hi, lo, counts);
    k_gemm   <<<636,  512, 0, stream>>>(hi, lo, counts);
    k_seedrow<<<512,  256, 0, stream>>>(A, counts, attn, simrow, seedp, outp);
    k_subsel <<<128,  512, 0, stream>>>(A, simrow, seedp, act, Mp, subsim);
    k_fin    <<<1,    256, 0, stream>>>(subsim, act, Mp, outp);
}

// Round 19
// 164.140 us; speedup vs baseline: 1.0665x; 1.0665x over previous
//
#include <hip/hip_runtime.h>
#include <cstdint>

#define NP   4096      // patches
#define DD   768       // embed dim
#define HD   64
#define WD   64
#define KTOP 100

typedef short bf16x8 __attribute__((ext_vector_type(8)));
typedef float f32x4  __attribute__((ext_vector_type(4)));

__device__ __forceinline__ void gload_lds16(const void* g, void* l) {
    __builtin_amdgcn_global_load_lds(
        (const __attribute__((address_space(1))) unsigned int*)(uintptr_t)g,
        (__attribute__((address_space(3))) unsigned int*)(unsigned int)(uintptr_t)l,
        16, 0, 0);
}

__device__ __forceinline__ unsigned short f2bf_rne(float x) {
    unsigned b = __float_as_uint(x);
    unsigned r = b + 0x7FFFu + ((b >> 16) & 1u);
    return (unsigned short)(r >> 16);
}
__device__ __forceinline__ float bf2f(unsigned short h) {
    return __uint_as_float(((unsigned)h) << 16);
}

// ---------------- kernel 1: split A into bf16 hi+lo; zero counts ----------------
__global__ __launch_bounds__(256) void k_split(const float* __restrict__ A,
                                               unsigned short* __restrict__ hi,
                                               unsigned short* __restrict__ lo,
                                               int* __restrict__ counts) {
    if (blockIdx.x < 16) counts[blockIdx.x * 256 + threadIdx.x] = 0;
    int idx = blockIdx.x * 256 + threadIdx.x;       // float4 index
    float4 v = ((const float4*)A)[idx];
    unsigned short h0 = f2bf_rne(v.x), h1 = f2bf_rne(v.y),
                   h2 = f2bf_rne(v.z), h3 = f2bf_rne(v.w);
    unsigned short l0 = f2bf_rne(v.x - bf2f(h0)), l1 = f2bf_rne(v.y - bf2f(h1)),
                   l2 = f2bf_rne(v.z - bf2f(h2)), l3 = f2bf_rne(v.w - bf2f(h3));
    ((ushort4*)hi)[idx] = make_ushort4(h0, h1, h2, h3);
    ((ushort4*)lo)[idx] = make_ushort4(l0, l1, l2, l3);
}

// ---------------- kernel 2: split-bf16 MFMA GEMM, mixed-granularity grid ----------------
// R19 = REVERT to R17's GEMM (best measured: total 164.4 us, gemm 47.6).
// R18's BK=64 full path regressed (59.2 us): 128 KB LDS cut occupancy
// 30.5->17.7% (66.5 KB allowed partial 2nd-block co-residency) and the 64 KB
// prefetch window pushed FETCH 37.4->42.2 MB. Falsifier fired; GEMM exhausted.
// Full path: BK=32, 24 iters (R7 lineage, 19.1 us/tile, 0 conflicts).
// Tail: 124 eighth tiles (64x32, BK=64, 12 iters) backfilling the third round.
__device__ __forceinline__ void stage_full(const unsigned short* __restrict__ hi,
                                           const unsigned short* __restrict__ lo,
                                           int i0, int j0, int kbase, int tid,
                                           unsigned short* G) {
#pragma unroll
    for (int q = 0; q < 4; ++q) {
        int pp = q * 512 + tid;                  // 0..2047 (A:0-1023, B:1024-2047)
        int ppt = pp & 1023;
        int row = ppt >> 3;
        int kcl = (ppt & 7) ^ (row & 7);         // logical chunk (inverse of swizzle)
        int rbase = (pp < 1024) ? i0 : j0;
        const unsigned short* src =
            ((kcl < 4) ? hi : lo) + (size_t)(rbase + row) * DD + kbase + (kcl & 3) * 8;
        gload_lds16(src, G + pp * 8);
    }
}

// eighth tile (64 A-rows, 32 B-rows), BK=64: 1536 chunks/buffer, 3 per thread
__device__ __forceinline__ void stage_eighth(const unsigned short* __restrict__ hi,
                                             const unsigned short* __restrict__ lo,
                                             int i0, int j0, int kbase, int tid,
                                             unsigned short* G) {
#pragma unroll
    for (int q = 0; q < 3; ++q) {
        int pp = q * 512 + tid;                  // 0..1535
        int ww = (pp >= 768) ? 1 : 0;            // 32-K window
        int ppt = pp - ww * 768;                 // 0..767 within window
        int isB = ppt >= 512;
        int rowp = (isB ? (ppt - 512) : ppt) >> 3;   // A:0..63  B:0..31
        int kcl = (ppt & 7) ^ (rowp & 7);
        int rbase = isB ? j0 : i0;
        const unsigned short* src =
            ((kcl < 4) ? hi : lo) + (size_t)(rbase + rowp) * DD
            + kbase + ww * 32 + (kcl & 3) * 8;
        gload_lds16(src, G + pp * 8);
    }
}

__global__ __launch_bounds__(512, 4) void k_gemm(const unsigned short* __restrict__ hi,
                                                 const unsigned short* __restrict__ lo,
                                                 int* __restrict__ counts) {
    __shared__ __align__(16) unsigned short G[2][2048 * 8];   // 2 x 32 KB
    __shared__ int colc[128];
    __shared__ int rowc[128];

    int job = blockIdx.x;
    int p, er = 0, ec = 0, offd_tail = 1;
    if (job < 512) {
        p = job;
    } else {
        int r = job - 512;                       // 0..123
        p = 512;
        for (;;) {
            int nj = (p == 523 || p == 527) ? 6 : 8;
            if (r < nj) break;
            r -= nj; ++p;
        }
        if (p == 523 || p == 527) {
            // 0:(0,0)D 1:(0,1)D 2:(1,2)D 3:(1,3)D 4:(0,2)O 5:(0,3)O
            if (r < 4) { er = r >> 1; ec = (r >> 1) * 2 + (r & 1); offd_tail = 0; }
            else       { er = 0; ec = r - 2; offd_tail = 1; }
        } else {
            er = r >> 2; ec = r & 3; offd_tail = 1;
        }
    }

    // XCD-locality supertile remap (bijective over 0..527):
    int t = ((p & 7) * 66) + (p >> 3);
    int SI = 0, SJ = 0, rem = t;
    for (;;) {
        int sz = (SI == SJ) ? 36 : 64;
        if (rem < sz) break;
        rem -= sz;
        if (++SJ == 4) { ++SI; SJ = SI; }
    }
    int li, lj;
    if (SI == SJ) {
        int r2 = 0;
        while (rem >= (8 - r2)) { rem -= (8 - r2); ++r2; }
        li = r2; lj = r2 + rem;
    } else { li = rem >> 3; lj = rem & 7; }
    int bi = SI * 8 + li, bj = SJ * 8 + lj;

    int tid = threadIdx.x;
    int lane = tid & 63, w = tid >> 6;   // w 0..7
    int kcf = lane >> 4;                 // 0..3
    int nl = lane & 15;                  // col within 16x16 tile
    int rg = lane >> 4;                  // row group (rows rg*4 + g)

    if (job < 512) {
        // ---------------- FULL 128x128 path (R7/R13/R14 verbatim) ----------------
        int wm = w & 1, wn = w >> 1;
        int i0 = bi * 128, j0 = bj * 128;
        int offd = (bi != bj);
        int paH[4], paL[4], pbH[2], pbL[2];
#pragma unroll
        for (int tt = 0; tt < 4; ++tt) {
            int arow = wm * 64 + tt * 16 + (lane & 15);
            paH[tt] = arow * 8 + (kcf ^ (arow & 7));
            paL[tt] = arow * 8 + ((kcf + 4) ^ (arow & 7));
        }
#pragma unroll
        for (int u = 0; u < 2; ++u) {
            int brow = wn * 32 + u * 16 + (lane & 15);
            pbH[u] = 1024 + brow * 8 + (kcf ^ (brow & 7));
            pbL[u] = 1024 + brow * 8 + ((kcf + 4) ^ (brow & 7));
        }
        f32x4 acc[4][2];
#pragma unroll
        for (int ti = 0; ti < 4; ++ti)
#pragma unroll
            for (int u = 0; u < 2; ++u) { acc[ti][u][0] = 0.f; acc[ti][u][1] = 0.f;
                                          acc[ti][u][2] = 0.f; acc[ti][u][3] = 0.f; }

        stage_full(hi, lo, i0, j0, 0, tid, G[0]);
        for (int it = 0; it < 24; ++it) {
            int cur = it & 1;
            __syncthreads();
            if (it + 1 < 24)
                stage_full(hi, lo, i0, j0, (it + 1) * 32, tid, G[cur ^ 1]);
            bf16x8 ahi[4], alo[4], bhi[2], blo[2];
#pragma unroll
            for (int tt = 0; tt < 4; ++tt) {
                ahi[tt] = *(const bf16x8*)&G[cur][paH[tt] * 8];
                alo[tt] = *(const bf16x8*)&G[cur][paL[tt] * 8];
            }
#pragma unroll
            for (int u = 0; u < 2; ++u) {
                bhi[u] = *(const bf16x8*)&G[cur][pbH[u] * 8];
                blo[u] = *(const bf16x8*)&G[cur][pbL[u] * 8];
            }
#pragma unroll
            for (int ti = 0; ti < 4; ++ti)
#pragma unroll
                for (int u = 0; u < 2; ++u) {
                    acc[ti][u] = __builtin_amdgcn_mfma_f32_16x16x32_bf16(
                        ahi[ti], bhi[u], acc[ti][u], 0, 0, 0);
                    acc[ti][u] = __builtin_amdgcn_mfma_f32_16x16x32_bf16(
                        alo[ti], bhi[u], acc[ti][u], 0, 0, 0);
                    acc[ti][u] = __builtin_amdgcn_mfma_f32_16x16x32_bf16(
                        ahi[ti], blo[u], acc[ti][u], 0, 0, 0);
                }
        }

        if (tid < 128) { colc[tid] = 0; rowc[tid] = 0; }
        __syncthreads();
        int cc[2] = {0, 0};
#pragma unroll
        for (int ti = 0; ti < 4; ++ti)
#pragma unroll
            for (int u = 0; u < 2; ++u) {
                f32x4 a = acc[ti][u];
                cc[u] += ((a[0] >= 0.f) ? 1 : 0) + ((a[1] >= 0.f) ? 1 : 0) +
                         ((a[2] >= 0.f) ? 1 : 0) + ((a[3] >= 0.f) ? 1 : 0);
            }
#pragma unroll
        for (int u = 0; u < 2; ++u) {
            int v = cc[u];
            v += __shfl_xor(v, 16);
            v += __shfl_xor(v, 32);
            if (rg == 0) atomicAdd(&colc[wn * 32 + u * 16 + nl], v);
        }
        if (offd) {
#pragma unroll
            for (int ti = 0; ti < 4; ++ti)
#pragma unroll
                for (int g = 0; g < 4; ++g) {
                    int rv = ((acc[ti][0][g] >= 0.f) ? 1 : 0) +
                             ((acc[ti][1][g] >= 0.f) ? 1 : 0);
                    rv += __shfl_xor(rv, 1);
                    rv += __shfl_xor(rv, 2);
                    rv += __shfl_xor(rv, 4);
                    rv += __shfl_xor(rv, 8);
                    if (nl == 0) atomicAdd(&rowc[wm * 64 + ti * 16 + rg * 4 + g], rv);
                }
        }
        __syncthreads();
        if (tid < 128) {
            atomicAdd(&counts[j0 + tid], colc[tid]);
            if (offd) atomicAdd(&counts[i0 + tid], rowc[tid]);
        }
    } else {
        // ---------------- EIGHTH 64x32 path, BK=64 (tail round) ----------------
        int wm2 = w >> 1, wn2 = w & 1;           // row group x16 (0..3), col group x16 (0..1)
        int i0 = bi * 128 + er * 64, j0 = bj * 128 + ec * 32;
        int offd = offd_tail;

        int arow = wm2 * 16 + (lane & 15);       // 0..63
        int brow = wn2 * 16 + (lane & 15);       // 0..31
        int paH[2], paL[2], pbH[2], pbL[2];
#pragma unroll
        for (int ww = 0; ww < 2; ++ww) {
            paH[ww] = ww * 768 + arow * 8 + (kcf ^ (arow & 7));
            paL[ww] = ww * 768 + arow * 8 + ((kcf + 4) ^ (arow & 7));
            pbH[ww] = ww * 768 + 512 + brow * 8 + (kcf ^ (brow & 7));
            pbL[ww] = ww * 768 + 512 + brow * 8 + ((kcf + 4) ^ (brow & 7));
        }

        f32x4 acc = {0.f, 0.f, 0.f, 0.f};

        stage_eighth(hi, lo, i0, j0, 0, tid, G[0]);
        for (int it = 0; it < 12; ++it) {
            int cur = it & 1;
            __syncthreads();
            if (it + 1 < 12)
                stage_eighth(hi, lo, i0, j0, (it + 1) * 64, tid, G[cur ^ 1]);
#pragma unroll
            for (int ww = 0; ww < 2; ++ww) {
                bf16x8 ah = *(const bf16x8*)&G[cur][paH[ww] * 8];
                bf16x8 al = *(const bf16x8*)&G[cur][paL[ww] * 8];
                bf16x8 bh = *(const bf16x8*)&G[cur][pbH[ww] * 8];
                bf16x8 bl = *(const bf16x8*)&G[cur][pbL[ww] * 8];
                acc = __builtin_amdgcn_mfma_f32_16x16x32_bf16(ah, bh, acc, 0, 0, 0);
                acc = __builtin_amdgcn_mfma_f32_16x16x32_bf16(al, bh, acc, 0, 0, 0);
                acc = __builtin_amdgcn_mfma_f32_16x16x32_bf16(ah, bl, acc, 0, 0, 0);
            }
        }

        int* colq = colc;            // 32 ints
        int* rowq = colc + 32;       // 64 ints
        if (tid < 96) colc[tid] = 0;
        __syncthreads();
        {
            int v = ((acc[0] >= 0.f) ? 1 : 0) + ((acc[1] >= 0.f) ? 1 : 0) +
                    ((acc[2] >= 0.f) ? 1 : 0) + ((acc[3] >= 0.f) ? 1 : 0);
            v += __shfl_xor(v, 16);
            v += __shfl_xor(v, 32);
            if (rg == 0) atomicAdd(&colq[wn2 * 16 + nl], v);
        }
        if (offd) {
#pragma unroll
            for (int g = 0; g < 4; ++g) {
                int rv = ((acc[g] >= 0.f) ? 1 : 0);
                rv += __shfl_xor(rv, 1);
                rv += __shfl_xor(rv, 2);
                rv += __shfl_xor(rv, 4);
                rv += __shfl_xor(rv, 8);
                if (nl == 0) atomicAdd(&rowq[wm2 * 16 + rg * 4 + g], rv);
            }
        }
        __syncthreads();
        if (tid < 32) atomicAdd(&counts[j0 + tid], colq[tid]);
        if (tid < 64 && offd) atomicAdd(&counts[i0 + tid], rowq[tid]);
    }
}

// ---------------- shared helpers (8-wave, 512 threads) ----------------
__device__ __forceinline__ int block_sum512(int v, int lane, int w, int* wred) {
#pragma unroll
    for (int o = 1; o < 64; o <<= 1) v += __shfl_xor(v, o);
    if (lane == 0) wred[w] = v;
    __syncthreads();
    int tt = 0;
#pragma unroll
    for (int i = 0; i < 8; ++i) tt += wred[i];
    __syncthreads();
    return tt;
}
__device__ __forceinline__ int block_exscan512(int v, int lane, int w, int* wred,
                                               int* total) {
    int inc = v;
#pragma unroll
    for (int o = 1; o < 64; o <<= 1) { int u = __shfl_up(inc, o); if (lane >= o) inc += u; }
    if (lane == 63) wred[w] = inc;
    __syncthreads();
    int wofs = 0, tot = 0;
#pragma unroll
    for (int i = 0; i < 8; ++i) { int x = wred[i]; if (i < w) wofs += x; tot += x; }
    *total = tot;
    __syncthreads();
    return wofs + inc - v;   // exclusive
}

// ---------------- kernel 3: argmin seed (packed-key wave-min) + simrow + zero outp ----
// 512 blocks (8 rows each, 2 rows/wave). Argmin via key=(count<<12|j) min
// (lexicographic: min count then min index -- identical tie-break), ONE barrier.
__global__ __launch_bounds__(256) void k_seedrow(const float* __restrict__ A,
                                                 const int* __restrict__ counts,
                                                 const int* __restrict__ attn_seed,
                                                 float* __restrict__ simrow,
                                                 int* __restrict__ seedp,
                                                 int* __restrict__ outp) {
    __shared__ unsigned redw[4];
    int tid = threadIdx.x, lane = tid & 63, w = tid >> 6;
    int blk = blockIdx.x;

    unsigned bk = 0xFFFFFFFFu;
    for (int j = tid; j < NP; j += 256) {
        unsigned k2 = ((unsigned)counts[j] << 12) | (unsigned)j;   // c<=4096 -> 25 bits
        bk = min(bk, k2);
    }
#pragma unroll
    for (int o = 1; o < 64; o <<= 1) {
        unsigned ok = __shfl_xor(bk, o);
        bk = min(bk, ok);
    }
    if (lane == 0) redw[w] = bk;
    __syncthreads();
    unsigned m0 = min(min(redw[0], redw[1]), min(redw[2], redw[3]));
    int flat = (int)(m0 & 0xFFFu);

    int sr = flat / WD, sc = flat % WD;
    int vr = sr + attn_seed[0];
    int vc = sc + attn_seed[1];
    int rr, rc;
    if ((vr & 1) == 0) rr = vr >> 1;
    else { int m = vr >> 1; rr = (m & 1) ? m + 1 : m; }   // round-half-to-even
    if ((vc & 1) == 0) rc = vc >> 1;
    else { int m = vc >> 1; rc = (m & 1) ? m + 1 : m; }
    int seed = rr * WD + rc;
    if (blk == 0 && tid == 0) seedp[0] = seed;

    float sv[12];
#pragma unroll
    for (int kk = 0; kk < 12; ++kk) sv[kk] = A[(size_t)seed * DD + lane + kk * 64];
    int jbase = blk * 8 + w * 2;
#pragma unroll
    for (int jj = 0; jj < 2; ++jj) {
        int j = jbase + jj;
        float sum = 0.f;
#pragma unroll
        for (int kk = 0; kk < 12; ++kk)
            sum += sv[kk] * A[(size_t)j * DD + lane + kk * 64];
#pragma unroll
        for (int o = 32; o > 0; o >>= 1) sum += __shfl_down(sum, o);
        if (lane == 0) simrow[j] = sum;
    }
    if (blk < 128 && tid < 32) outp[blk * 32 + tid] = 0;
}

// ---------------- kernel 4: fused top-K select + subsim row (128 blocks, 512 thr) ----
// 8 waves: radix on 8 keys/thread; subsim q-loop q+=8 (13 serial iterations).
// Selection invariants unchanged (ascending-j key blocks per tid order).
__global__ __launch_bounds__(512) void k_subsel(const float* __restrict__ A,
                                                const float* __restrict__ simrow,
                                                const int* __restrict__ seedp,
                                                int* __restrict__ act, int* __restrict__ Mp,
                                                float* __restrict__ subsim) {
    __shared__ int wred[8];
    __shared__ unsigned long long rsl[16][8];
    __shared__ int act_s[128];
    __shared__ float av[DD];
    int tid = threadIdx.x, lane = tid & 63, w = tid >> 6;   // w 0..7
    int seed = seedp[0];
    int base = tid * 8;
    unsigned key[8];
#pragma unroll
    for (int n = 0; n < 8; ++n) {
        unsigned b = __float_as_uint(simrow[base + n]);
        key[n] = (b & 0x80000000u) ? ~b : (b | 0x80000000u);   // monotone encode
    }
    unsigned prefix = 0;
    for (int pass = 0; pass < 16; ++pass) {
        int shift = 30 - pass * 2;
        unsigned phi = prefix >> shift;        // low 2 bits zero
        int s0 = 0, s1 = 0, s2 = 0, s3 = 0;
#pragma unroll
        for (int n = 0; n < 8; ++n) {
            unsigned hv = key[n] >> shift;
            s0 += (hv >= phi) ? 1 : 0;
            s1 += (hv >= phi + 1) ? 1 : 0;
            s2 += (hv >= phi + 2) ? 1 : 0;
            s3 += (hv >= phi + 3) ? 1 : 0;
        }
        unsigned long long pk = (unsigned long long)(unsigned)s0 |
                                ((unsigned long long)(unsigned)s1 << 16) |
                                ((unsigned long long)(unsigned)s2 << 32) |
                                ((unsigned long long)(unsigned)s3 << 48);
#pragma unroll
        for (int o = 1; o < 64; o <<= 1) {
            unsigned lo2 = __shfl_xor((unsigned)pk, o);
            unsigned hi2 = __shfl_xor((unsigned)(pk >> 32), o);
            pk += ((unsigned long long)hi2 << 32) | lo2;   // fields<=4096: no carry-out
        }
        if (lane == 0) rsl[pass][w] = pk;
        __syncthreads();
        unsigned long long tot = 0;
#pragma unroll
        for (int i = 0; i < 8; ++i) tot += rsl[pass][i];
        int c1 = (int)((tot >> 16) & 0xFFFF);
        int c2 = (int)((tot >> 32) & 0xFFFF);
        int c3 = (int)((tot >> 48) & 0xFFFF);
        int d = (c3 >= KTOP) ? 3 : (c2 >= KTOP) ? 2 : (c1 >= KTOP) ? 1 : 0;
        prefix |= (unsigned)d << shift;
    }
    unsigned KT = prefix;
    int cgt = 0, ceq = 0;
#pragma unroll
    for (int n = 0; n < 8; ++n) {
        cgt += (key[n] > KT) ? 1 : 0;
        ceq += (key[n] == KT) ? 1 : 0;
    }
    int totgt = block_sum512(cgt, lane, w, wred);
    int slots = KTOP - totgt;
    int dummy;
    int eqrun = block_exscan512(ceq, lane, w, wred, &dummy);
    int flag[8]; int cf = 0;
#pragma unroll
    for (int n = 0; n < 8; ++n) {
        int j = base + n;
        unsigned k = key[n];
        int topk = (k > KT) || (k == KT && eqrun < slots);
        if (k == KT) ++eqrun;
        int f = (topk && (k >= 0x80000000u || j == seed)) ? 1 : 0;
        flag[n] = f; cf += f;
    }
    int M;
    int off = block_exscan512(cf, lane, w, wred, &M);
#pragma unroll
    for (int n = 0; n < 8; ++n)
        if (flag[n]) act_s[off++] = base + n;
    __syncthreads();

    int p = blockIdx.x;
    if (p == 0) {
        if (tid == 0) Mp[0] = M;
        if (tid < M) act[tid] = act_s[tid];
    }
    if (p >= M) return;

    int ip = act_s[p];
    for (int k = tid; k < DD; k += 512) av[k] = A[(size_t)ip * DD + k];
    __syncthreads();
    for (int q = w; q < M; q += 8) {
        int iq = act_s[q];
        float sum = 0.f;
#pragma unroll
        for (int kk = 0; kk < 12; ++kk) {
            int k = lane + kk * 64;
            sum += av[k] * A[(size_t)iq * DD + k];
        }
#pragma unroll
        for (int o = 32; o > 0; o >>= 1) sum += __shfl_down(sum, o);
        if (lane == 0) subsim[p * 128 + q] = sum;
    }
}

// ---------------- kernel 5: expansion scan + CC (1 block) ----------------
__global__ __launch_bounds__(256) void k_fin(const float* __restrict__ subsim,
                                             const int* __restrict__ act,
                                             const int* __restrict__ Mp,
                                             int* __restrict__ outp) {
    __shared__ float ss[128 * 128];   // 64 KB, transposed+rotated
    __shared__ int act_s[128];
    __shared__ int alive[128];
    __shared__ int lab[128];
    __shared__ unsigned char nbr[128][8];
    __shared__ int ncnt[128];
    __shared__ int chg;
    int M = Mp[0];
    int tid = threadIdx.x, lane = tid & 63;

    if (tid < 128) act_s[tid] = (tid < M) ? act[tid] : 0;
    // ssT(q,p) at ss[q*128 + ((p+q)&127)]: conflict-free writes & column reads
    for (int i4 = tid; i4 < M * 32; i4 += 256) {
        int p = i4 >> 5, qb = (i4 & 31) << 2;
        float4 v = ((const float4*)subsim)[i4];
        ss[(qb + 0) * 128 + ((p + qb + 0) & 127)] = v.x;
        ss[(qb + 1) * 128 + ((p + qb + 1) & 127)] = v.y;
        ss[(qb + 2) * 128 + ((p + qb + 2) & 127)] = v.z;
        ss[(qb + 3) * 128 + ((p + qb + 3) & 127)] = v.w;
    }
    __syncthreads();

    // expansion scan with incremental sums
    if (tid < 64) {
        float S_lo = 0.f, S_hi = 0.f;
        for (int q = 0; q < M; ++q) {
            S_lo += ss[q * 128 + ((lane + q) & 127)];
            S_hi += ss[q * 128 + ((lane + 64 + q) & 127)];
        }
        float al = (lane < M) ? 1.f : 0.f;
        float ah = (lane + 64 < M) ? 1.f : 0.f;
        for (int p = 0; p < M; ++p) {
            float Sp = (p < 64) ? __shfl(S_lo, p) : __shfl(S_hi, p - 64);
            if (!(Sp > 0.f)) {   // node p dies: remove its column from all sums
                S_lo -= ss[p * 128 + ((lane + p) & 127)];
                S_hi -= ss[p * 128 + ((lane + 64 + p) & 127)];
                if (lane == p)      al = 0.f;
                if (lane + 64 == p) ah = 0.f;
            }
        }
        alive[lane]      = (lane < M && al != 0.f) ? 1 : 0;
        alive[lane + 64] = (lane + 64 < M && ah != 0.f) ? 1 : 0;
    }
    __syncthreads();

    // CC: neighbor lists + hook/pointer-jump
    if (tid < 128) {
        int a = (tid < M) ? alive[tid] : 0;
        int c = 0;
        if (a) {
            int id = act_s[tid];
            int y = id >> 6, x = id & 63;
            for (int q = 0; q < M; ++q) {
                if (q == tid || !alive[q]) continue;
                int qid = act_s[q];
                int dy = (qid >> 6) - y, dx = (qid & 63) - x;
                if (dy >= -1 && dy <= 1 && dx >= -1 && dx <= 1)
                    nbr[tid][c++] = (unsigned char)q;
            }
        }
        ncnt[tid] = c;
        lab[tid] = a ? tid : 32767;
    }
    __syncthreads();
    while (true) {
        if (tid == 0) chg = 0;
        __syncthreads();
        int local = 0;
        if (tid < M && alive[tid]) {
            int m = lab[tid];
            int nc = ncnt[tid];
            for (int k = 0; k < nc; ++k) { int u = lab[nbr[tid][k]]; if (u < m) m = u; }
            { int u = lab[m]; if (u < m) m = u; }   // jump
            { int u = lab[m]; if (u < m) m = u; }   // jump again
            if (m < lab[tid]) { lab[tid] = m; local = 1; }
        }
        if (local) chg = 1;
        __syncthreads();
        if (chg == 0) break;
        __syncthreads();
    }
    if (tid < M && alive[tid]) outp[act_s[tid]] = act_s[lab[tid]] + 1;
}

extern "C" void kernel_launch(void* const* d_in, const int* in_sizes, int n_in,
                              void* d_out, int out_size, void* d_ws, size_t ws_size,
                              hipStream_t stream) {
    const float* A = (const float*)d_in[0];       // out: (4096, 768) fp32
    const int* attn = (const int*)d_in[1];        // attn_seed: (2,) int32
    int* outp = (int*)d_out;                      // labels: (64,64) int32

    char* ws = (char*)d_ws;
    int*            counts = (int*)(ws);                    // 16 KB
    float*          simrow = (float*)(ws + 16384);          // 16 KB
    int*            act    = (int*)(ws + 32768);            // 512 B
    int*            Mp     = (int*)(ws + 33280);
    int*            seedp  = (int*)(ws + 33284);
    float*          subsim = (float*)(ws + 33792);          // 64 KB
    unsigned short* hi     = (unsigned short*)(ws + 1048576);           // 6.29 MB
    unsigned short* lo     = (unsigned short*)(ws + 1048576 + 6291456); // 6.29 MB

    k_split  <<<3072, 256, 0, stream>>>(A, hi, lo, counts);
    k_gemm   <<<636,  512, 0, stream>>>(hi, lo, counts);
    k_seedrow<<<512,  256, 0, stream>>>(A, counts, attn, simrow, seedp, outp);
    k_subsel <<<128,  512, 0, stream>>>(A, simrow, seedp, act, Mp, subsim);
    k_fin    <<<1,    256, 0, stream>>>(subsim, act, Mp, outp);
}